// Round 2
// baseline (267.846 us; speedup 1.0000x reference)
//
#include <hip/hip_runtime.h>
#include <hip/hip_bf16.h>
#include <stdint.h>

// Problem constants: B=2, S=2048, H=1024, NH=16, HD=64, K=1024
// Inputs are FP32 (reference dtypes); compute in bf16 MFMA; output FP32.

typedef __attribute__((ext_vector_type(8))) short short8;
typedef __attribute__((ext_vector_type(4))) float floatx4;
typedef __attribute__((ext_vector_type(4))) unsigned int uint4v;

__device__ __forceinline__ unsigned short f2bf(float f) {
    unsigned int u = __float_as_uint(f);
    unsigned int r = u + 0x7fffu + ((u >> 16) & 1u);
    return (unsigned short)(r >> 16);
}
__device__ __forceinline__ float bf2f(unsigned short u) {
    return __uint_as_float(((unsigned int)u) << 16);
}

// ---------------------------------------------------------------------------
// fp32 -> bf16 conversion, 4 elements/thread, vectorized loads.
// ---------------------------------------------------------------------------
__global__ __launch_bounds__(256)
void cvt_f32_bf16(const float* __restrict__ in, unsigned short* __restrict__ out, int n4)
{
    int i = blockIdx.x * 256 + threadIdx.x;
    if (i >= n4) return;
    float4 v = *(const float4*)(in + (size_t)i * 4);
    unsigned short o[4] = { f2bf(v.x), f2bf(v.y), f2bf(v.z), f2bf(v.w) };
    *(uint2*)(out + (size_t)i * 4) = *(uint2*)o;
}

// ---------------------------------------------------------------------------
// NT GEMM: C[M,N] = A[M,K] * B[N,K]^T, bf16 in, fp32 MFMA accum. K=1024.
// 128x128 block tile, BK=64, 4 waves each 64x64 (4x4 of 16x16x32 MFMA).
// MODE 0: scatter bf16 epilogue into q/k/v buffers [B,NH,S,HD].
// MODE 1: plain fp32 store outf[m*N+n].
// LDS: A-tile 16KB + B-tile 16KB, XOR-8 swizzle on 16B k-chunks:
//   chunk (row, c) lives at row*128 + ((c ^ (row&7))*16) bytes.
// ---------------------------------------------------------------------------
template<int MODE>
__global__ __launch_bounds__(256, 2)
void gemm_nt(const unsigned short* __restrict__ A,
             const unsigned short* __restrict__ Bm,
             unsigned short* __restrict__ out0,
             unsigned short* __restrict__ out1,
             unsigned short* __restrict__ out2,
             float* __restrict__ outf,
             int N)
{
    __shared__ unsigned char smem[32768];
    const int K = 1024;
    const int tid  = threadIdx.x;
    const int wave = tid >> 6, lane = tid & 63;
    const int l15  = lane & 15, quad = lane >> 4;
    const int wm = wave >> 1, wn = wave & 1;
    const int bm = blockIdx.y, bn = blockIdx.x;

    floatx4 acc[4][4];
#pragma unroll
    for (int i = 0; i < 4; i++)
#pragma unroll
        for (int j = 0; j < 4; j++)
            acc[i][j] = floatx4{0.f, 0.f, 0.f, 0.f};

    // staging map: slot s in [0,1024): row = s>>3, cs = s&7, chunk c = cs^(row&7)
    int srow[4], scol[4];
#pragma unroll
    for (int l = 0; l < 4; l++) {
        int s = (wave * 4 + l) * 64 + lane;
        int row = s >> 3, cs = s & 7;
        srow[l] = row;
        scol[l] = (cs ^ (row & 7)) * 8;   // element offset within row
    }

    const unsigned short* Abase = A  + (size_t)(bm * 128) * K;
    const unsigned short* Bbase = Bm + (size_t)(bn * 128) * K;

    for (int k0 = 0; k0 < K; k0 += 64) {
        __syncthreads();
#pragma unroll
        for (int l = 0; l < 4; l++) {
            int s = (wave * 4 + l) * 64 + lane;
            uint4v va = *(const uint4v*)(Abase + (size_t)srow[l] * K + k0 + scol[l]);
            *(uint4v*)(&smem[s * 16]) = va;
            uint4v vb = *(const uint4v*)(Bbase + (size_t)srow[l] * K + k0 + scol[l]);
            *(uint4v*)(&smem[16384 + s * 16]) = vb;
        }
        __syncthreads();
#pragma unroll
        for (int s2 = 0; s2 < 2; s2++) {
            short8 af[4], bfr[4];
            int c = s2 * 4 + quad;
#pragma unroll
            for (int i = 0; i < 4; i++) {
                int row = wm * 64 + i * 16 + l15;
                af[i] = *(const short8*)(&smem[row * 128 + ((c ^ (row & 7)) * 16)]);
            }
#pragma unroll
            for (int j = 0; j < 4; j++) {
                int row = wn * 64 + j * 16 + l15;
                bfr[j] = *(const short8*)(&smem[16384 + row * 128 + ((c ^ (row & 7)) * 16)]);
            }
#pragma unroll
            for (int i = 0; i < 4; i++)
#pragma unroll
                for (int j = 0; j < 4; j++)
                    acc[i][j] = __builtin_amdgcn_mfma_f32_16x16x32_bf16(af[i], bfr[j], acc[i][j], 0, 0, 0);
        }
    }

    // epilogue: lane element (i,j,r): m = bm*128+wm*64+i*16+quad*4+r, n = bn*128+wn*64+j*16+l15
#pragma unroll
    for (int i = 0; i < 4; i++) {
#pragma unroll
        for (int j = 0; j < 4; j++) {
            int n = bn * 128 + wn * 64 + j * 16 + l15;
#pragma unroll
            for (int r = 0; r < 4; r++) {
                int m = bm * 128 + wm * 64 + i * 16 + quad * 4 + r;
                float fv = acc[i][j][r];
                if (MODE == 1) {
                    outf[(size_t)m * N + n] = fv;
                } else {
                    int t = n >> 10;            // 0=q 1=k 2=v
                    int h = (n >> 6) & 15;
                    int d = n & 63;
                    int b = m >> 11, si = m & 2047;
                    size_t off = (((size_t)(b * 16 + h)) * 2048 + si) * 64 + d;
                    unsigned short* dst = (t == 0) ? out0 : (t == 1 ? out1 : out2);
                    dst[off] = f2bf(fv);
                }
            }
        }
    }
}

// ---------------------------------------------------------------------------
// Flash attention: per block (b,h) x 128 q-rows. 4 waves x 32 q-rows each.
// K-chunks of 128 keys. LDS: K-tile 16KB (swizzled) + Vt 16KB (chunk-major
// transposed) + P 32KB (per-wave regions). Online softmax in registers.
// mask/gate read as fp32.
// ---------------------------------------------------------------------------
__global__ __launch_bounds__(256, 2)
void attn_kernel(const unsigned short* __restrict__ Qb,
                 const unsigned short* __restrict__ Kb,
                 const unsigned short* __restrict__ Vb,
                 const float* __restrict__ maskb,
                 const float* __restrict__ gateb,
                 unsigned short* __restrict__ ctx)
{
    __shared__ unsigned char smem[65536];
    const int S = 2048, HD = 64;
    const int tid  = threadIdx.x;
    const int wave = tid >> 6, lane = tid & 63;
    const int l15  = lane & 15, quad = lane >> 4;
    const int bh = blockIdx.y;
    const int b = bh >> 4, h = bh & 15;
    const int q0 = blockIdx.x * 128 + wave * 32;

    const size_t headoff = (size_t)bh * S * HD;
    const unsigned short* Qh = Qb + headoff;
    const unsigned short* Kh = Kb + headoff;
    const unsigned short* Vh = Vb + headoff;
    const float* maskp = maskb + (size_t)b * S;

    // Q fragments (A-operand): aq[sub][s2]; A[m=lane&15][k=quad*8+j]
    short8 aq[2][2];
#pragma unroll
    for (int sub = 0; sub < 2; sub++)
#pragma unroll
        for (int s2 = 0; s2 < 2; s2++)
            aq[sub][s2] = *(const short8*)(Qh + (size_t)(q0 + sub * 16 + l15) * HD + s2 * 32 + quad * 8);

    floatx4 o[2][4];
    float m_run[2][4], l_run[2][4];
#pragma unroll
    for (int sub = 0; sub < 2; sub++)
#pragma unroll
        for (int r = 0; r < 4; r++) { m_run[sub][r] = -1e30f; l_run[sub][r] = 0.f; }
#pragma unroll
    for (int sub = 0; sub < 2; sub++)
#pragma unroll
        for (int jt = 0; jt < 4; jt++) o[sub][jt] = floatx4{0.f, 0.f, 0.f, 0.f};

    const float sc = 0.125f;           // 1/sqrt(64)
    const float LOG2E = 1.44269504f;

    for (int kc = 0; kc < 16; kc++) {
        int kbase = kc * 128;
        __syncthreads();

        // stage K-tile (swizzled, same scheme as GEMM)
#pragma unroll
        for (int l = 0; l < 4; l++) {
            int s = (wave * 4 + l) * 64 + lane;
            int row = s >> 3, cs = s & 7;
            int c = cs ^ (row & 7);
            uint4v v = *(const uint4v*)(Kh + (size_t)(kbase + row) * HD + c * 8);
            *(uint4v*)(&smem[s * 16]) = v;
        }
        // stage Vt chunk-major: slot (c2,d) at 16384 + (c2*64+d)*16 holds {V[c2*8+j][d]}
#pragma unroll
        for (int i2 = 0; i2 < 4; i2++) {
            int c2 = wave * 4 + i2;
            int kk0 = c2 * 8;
            short8 pv;
#pragma unroll
            for (int j = 0; j < 8; j++)
                pv[j] = (short)Vh[(size_t)(kbase + kk0 + j) * HD + lane];  // lane = d, coalesced 128B
            *(short8*)(&smem[16384 + (c2 * 64 + lane) * 16]) = pv;
        }
        // mask values for this chunk (col = t*16 + l15); fp32
        float mv[8];
#pragma unroll
        for (int t = 0; t < 8; t++) mv[t] = maskp[kbase + t * 16 + l15];
        __syncthreads();

        // QK^T: st[sub][t] covers q-rows (sub), keys t*16..+16
        floatx4 st[2][8];
#pragma unroll
        for (int sub = 0; sub < 2; sub++)
#pragma unroll
            for (int t = 0; t < 8; t++) st[sub][t] = floatx4{0.f, 0.f, 0.f, 0.f};
#pragma unroll
        for (int s2 = 0; s2 < 2; s2++) {
            int c = s2 * 4 + quad;
#pragma unroll
            for (int t = 0; t < 8; t++) {
                int row = t * 16 + l15;
                short8 kf = *(const short8*)(&smem[row * 128 + ((c ^ (row & 7)) * 16)]);
                st[0][t] = __builtin_amdgcn_mfma_f32_16x16x32_bf16(aq[0][s2], kf, st[0][t], 0, 0, 0);
                st[1][t] = __builtin_amdgcn_mfma_f32_16x16x32_bf16(aq[1][s2], kf, st[1][t], 0, 0, 0);
            }
        }

        // online softmax + write P (bf16) into per-wave LDS region
#pragma unroll
        for (int sub = 0; sub < 2; sub++) {
            int pb = 32768 + wave * 8192 + sub * 4096;
            float mn[4], al[4];
#pragma unroll
            for (int t = 0; t < 8; t++)
#pragma unroll
                for (int r = 0; r < 4; r++)
                    st[sub][t][r] = st[sub][t][r] * sc + mv[t];
#pragma unroll
            for (int r = 0; r < 4; r++) {
                float mx = st[sub][0][r];
#pragma unroll
                for (int t = 1; t < 8; t++) mx = fmaxf(mx, st[sub][t][r]);
                mx = fmaxf(mx, __shfl_xor(mx, 1));
                mx = fmaxf(mx, __shfl_xor(mx, 2));
                mx = fmaxf(mx, __shfl_xor(mx, 4));
                mx = fmaxf(mx, __shfl_xor(mx, 8));
                mn[r] = fmaxf(m_run[sub][r], mx);
                al[r] = exp2f((m_run[sub][r] - mn[r]) * LOG2E);
                m_run[sub][r] = mn[r];
            }
            float rs[4] = {0.f, 0.f, 0.f, 0.f};
#pragma unroll
            for (int t = 0; t < 8; t++) {
#pragma unroll
                for (int r = 0; r < 4; r++) {
                    float p = exp2f((st[sub][t][r] - mn[r]) * LOG2E);
                    rs[r] += p;
                    int ql = quad * 4 + r;
                    int kk = t * 16 + l15;
                    int c  = kk >> 3;
                    int off = pb + (((c ^ ql) * 16 + ql) * 16) + (kk & 7) * 2;
                    *(unsigned short*)(&smem[off]) = f2bf(p);
                }
            }
#pragma unroll
            for (int r = 0; r < 4; r++) {
                rs[r] += __shfl_xor(rs[r], 1);
                rs[r] += __shfl_xor(rs[r], 2);
                rs[r] += __shfl_xor(rs[r], 4);
                rs[r] += __shfl_xor(rs[r], 8);
                l_run[sub][r] = l_run[sub][r] * al[r] + rs[r];
            }
#pragma unroll
            for (int jt = 0; jt < 4; jt++)
#pragma unroll
                for (int r = 0; r < 4; r++)
                    o[sub][jt][r] *= al[r];
        }
        asm volatile("s_waitcnt lgkmcnt(0)" ::: "memory");

        // PV: o[sub][jt] += P(sub) * V
#pragma unroll
        for (int st4 = 0; st4 < 4; st4++) {
            int c = st4 * 4 + quad;
            short8 ap[2];
#pragma unroll
            for (int sub = 0; sub < 2; sub++) {
                int pb = 32768 + wave * 8192 + sub * 4096;
                ap[sub] = *(const short8*)(&smem[pb + (((c ^ l15) * 16 + l15) * 16)]);
            }
#pragma unroll
            for (int jt = 0; jt < 4; jt++) {
                int d = jt * 16 + l15;
                short8 bv = *(const short8*)(&smem[16384 + (c * 64 + d) * 16]);
                o[0][jt] = __builtin_amdgcn_mfma_f32_16x16x32_bf16(ap[0], bv, o[0][jt], 0, 0, 0);
                o[1][jt] = __builtin_amdgcn_mfma_f32_16x16x32_bf16(ap[1], bv, o[1][jt], 0, 0, 0);
            }
        }
    }

    // epilogue: ctx[b, q, h, d] = o / l * gate[h]   (layout [B,S,NH,HD] == [B,S,H])
    float gate_f = gateb[h];
#pragma unroll
    for (int sub = 0; sub < 2; sub++) {
#pragma unroll
        for (int jt = 0; jt < 4; jt++) {
            int d = jt * 16 + l15;
#pragma unroll
            for (int r = 0; r < 4; r++) {
                int q = q0 + sub * 16 + quad * 4 + r;
                float val = o[sub][jt][r] / l_run[sub][r] * gate_f;
                ctx[((size_t)(b * 2048 + q)) * 1024 + h * 64 + d] = f2bf(val);
            }
        }
    }
}

// ---------------------------------------------------------------------------
extern "C" void kernel_launch(void* const* d_in, const int* in_sizes, int n_in,
                              void* d_out, int out_size, void* d_ws, size_t ws_size,
                              hipStream_t stream)
{
    const float* hidden = (const float*)d_in[0]; // [2,2048,1024] fp32
    const float* mask   = (const float*)d_in[1]; // [2,1,1,2048]  fp32
    const float* w_qkv  = (const float*)d_in[2]; // [3072,1024]   fp32
    const float* w_out  = (const float*)d_in[3]; // [1024,1024]   fp32
    const float* gate   = (const float*)d_in[4]; // [16]          fp32
    float* out = (float*)d_out;                  // [2,2048,1024] fp32

    unsigned short* q_buf = (unsigned short*)d_ws;            // [2,16,2048,64] bf16
    unsigned short* k_buf = q_buf + 4194304;
    unsigned short* v_buf = k_buf + 4194304;
    unsigned short* c_buf = v_buf + 4194304;                  // [2,2048,1024]  bf16
    unsigned short* h_bf  = c_buf + 4194304;                  // hidden bf16
    unsigned short* wq_bf = h_bf  + 4194304;                  // w_qkv bf16
    unsigned short* wo_bf = wq_bf + 3145728;                  // w_out bf16

    // fp32 -> bf16 converts
    cvt_f32_bf16<<<4096, 256, 0, stream>>>(hidden, h_bf, 1048576);
    cvt_f32_bf16<<<3072, 256, 0, stream>>>(w_qkv, wq_bf, 786432);
    cvt_f32_bf16<<<1024, 256, 0, stream>>>(w_out, wo_bf, 262144);

    // QKV projection: [4096,1024] x [3072,1024]^T, scatter into q/k/v
    gemm_nt<0><<<dim3(24, 32), 256, 0, stream>>>(h_bf, wq_bf, q_buf, k_buf, v_buf, nullptr, 3072);
    // fused flash attention + gate, writes ctx [B,S,H] bf16
    attn_kernel<<<dim3(16, 32), 256, 0, stream>>>(q_buf, k_buf, v_buf, mask, gate, c_buf);
    // output projection: [4096,1024] x [1024,1024]^T -> out fp32
    gemm_nt<1><<<dim3(8, 32), 256, 0, stream>>>(c_buf, wo_bf, nullptr, nullptr, nullptr, out, 1024);
}